// Round 8
// baseline (341.906 us; speedup 1.0000x reference)
//
#include <hip/hip_runtime.h>

#define Bn 16
#define Sn 64
#define Cn 20
#define Tn 2048
#define TPB 256
#define KS 8            // K-slices for cov partial Grams
#define Kc (Tn / KS)    // 256
#define PITCH 260       // LDS row pitch in words (cov staging), 16B-aligned

// One MLP layer for 2 time points, activations LDS-resident, math pinned by
// inline asm: exactly one v_fma_f32 per MAC, accumulator forced to VGPR
// ("+v"), weight forced to SGPR operand ("s"). Rationale: R0-R6 showed the
// compiler emits ~2.2x the necessary VALU ops (busy 83us vs 37.6us FMA
// floor) for EVERY HIP-source structure — asm removes its freedom to bloat.
template <int NI, int NJ>
__device__ __forceinline__ void layerA(float2 (*act)[TPB], const int tid,
                                       const float* __restrict__ W,
                                       const float* __restrict__ bb)
{
    float a0[NJ], a1[NJ];
    #pragma unroll
    for (int j = 0; j < NJ; ++j) {
        const float bj = bb[j];
        a0[j] = bj; a1[j] = bj;
    }
    #pragma unroll
    for (int c = 0; c < NI; ++c) {
        const float2 x = act[c][tid];            // 1 ds_read_b64
        #pragma unroll
        for (int j = 0; j < NJ; ++j) {
            const float w = W[c * NJ + j];       // wave-uniform -> SGPR
            asm("v_fma_f32 %0, %1, %2, %0" : "+v"(a0[j]) : "v"(x.x), "s"(w));
            asm("v_fma_f32 %0, %1, %2, %0" : "+v"(a1[j]) : "v"(x.y), "s"(w));
        }
    }
    #pragma unroll
    for (int j = 0; j < NJ; ++j) {
        float2 o;
        o.x = fmaxf(a0[j], 0.f);
        o.y = fmaxf(a1[j], 0.f);
        act[j][tid] = o;                         // in-place: all reads done
    }
}

// ---------------- Kernel A: MLP. grid = B*S*4 ----------------
__global__ __launch_bounds__(256, 4) void mlp_kernel(
    const float* __restrict__ data,
    const float* __restrict__ W1, const float* __restrict__ b1,
    const float* __restrict__ W2, const float* __restrict__ b2,
    const float* __restrict__ W3, const float* __restrict__ b3,
    const float* __restrict__ W4, const float* __restrict__ b4,
    const float* __restrict__ W5, const float* __restrict__ b5,
    float* __restrict__ y, double* __restrict__ Rp)
{
    __shared__ float2 act[Cn][TPB];              // 40 KB, thread-private columns
    __shared__ double rbuf[TPB / 64];

    const int tid = threadIdx.x;
    const int bs = blockIdx.x >> 2;
    const int qt = blockIdx.x & 3;
    const float* base = data + (size_t)bs * Cn * Tn;
    const int t0 = qt * (Tn / 4) + tid * 2;

    #pragma unroll
    for (int c = 0; c < Cn; ++c)
        act[c][tid] = *(const float2*)&base[c * Tn + t0];   // 8B aligned

    layerA<20, 20>(act, tid, W1, b1);
    layerA<20, 20>(act, tid, W2, b2);
    layerA<20, 20>(act, tid, W3, b3);
    layerA<20, 10>(act, tid, W4, b4);

    // final layer 10 -> 1 (ReLU included), straight from LDS, asm-pinned
    float s0 = b5[0], s1 = b5[0];
    #pragma unroll
    for (int c = 0; c < 10; ++c) {
        const float2 x = act[c][tid];
        const float w = W5[c];
        asm("v_fma_f32 %0, %1, %2, %0" : "+v"(s0) : "v"(x.x), "s"(w));
        asm("v_fma_f32 %0, %1, %2, %0" : "+v"(s1) : "v"(x.y), "s"(w));
    }
    s0 = fmaxf(s0, 0.f);
    s1 = fmaxf(s1, 0.f);

    float2 st; st.x = s0; st.y = s1;
    *(float2*)&y[(size_t)bs * Tn + t0] = st;

    // block row-sum for the mean: wave shuffle reduce, then 4-way LDS combine
    double r = (double)s0 + (double)s1;
    #pragma unroll
    for (int off = 32; off > 0; off >>= 1) r += __shfl_down(r, off, 64);
    if ((tid & 63) == 0) rbuf[tid >> 6] = r;
    __syncthreads();
    if (tid == 0) Rp[blockIdx.x] = rbuf[0] + rbuf[1] + rbuf[2] + rbuf[3];
}

// ---------------- Kernel B: Gram partials, NO ATOMICS (R7 form, unchanged) ----------------
// grid = Bn * KS (=128). Block (b,ks) stages 64 rows x Kc=256 centered fp32
// in LDS, computes the 64x64 partial Gram for its K-slice (4x4 per thread),
// stores to a private slice covp[(b*KS+ks)*4096 + s*64 + u].
__global__ __launch_bounds__(256) void cov_kernel(
    const float* __restrict__ y, const double* __restrict__ Rp,
    float* __restrict__ covp)
{
    __shared__ __align__(16) float S[64 * PITCH];   // ~66.5 KB
    __shared__ double smean[64];

    const int tid = threadIdx.x;
    const int b  = blockIdx.x >> 3;
    const int ks = blockIdx.x & 7;

    if (tid < 64) {
        const int q = ((b << 6) + tid) * 4;
        smean[tid] = (Rp[q] + Rp[q + 1] + Rp[q + 2] + Rp[q + 3]) * (1.0 / Tn);
    }
    __syncthreads();

    // stage: 64 rows x Kc floats, centered (fp64 mean), fp32 in LDS
    const float* ybase = y + (size_t)(b << 6) * Tn + ks * Kc;
    #pragma unroll
    for (int it = 0; it < (64 * Kc / 4) / TPB; ++it) {   // 16 iters
        const int f4 = tid + it * TPB;
        const int row = f4 >> 6;                          // Kc/4 = 64 float4 per row
        const int k4 = f4 & 63;
        const float4 v = *(const float4*)&ybase[(size_t)row * Tn + k4 * 4];
        const double m = smean[row];
        float4 c;
        c.x = (float)((double)v.x - m);
        c.y = (float)((double)v.y - m);
        c.z = (float)((double)v.z - m);
        c.w = (float)((double)v.w - m);
        *(float4*)&S[row * PITCH + k4 * 4] = c;
    }
    __syncthreads();

    // compute: thread (ty,tx) -> rows {ty+16a}, cols {tx+16j}
    const int ty = tid >> 4, tx = tid & 15;
    float acc[4][4];
    #pragma unroll
    for (int a = 0; a < 4; ++a)
        #pragma unroll
        for (int j = 0; j < 4; ++j) acc[a][j] = 0.f;

    for (int kq = 0; kq < Kc / 4; ++kq) {
        float4 av[4], bv[4];
        #pragma unroll
        for (int a = 0; a < 4; ++a) av[a] = *(const float4*)&S[(ty + 16 * a) * PITCH + kq * 4];
        #pragma unroll
        for (int j = 0; j < 4; ++j) bv[j] = *(const float4*)&S[(tx + 16 * j) * PITCH + kq * 4];
        #pragma unroll
        for (int a = 0; a < 4; ++a)
            #pragma unroll
            for (int j = 0; j < 4; ++j) {
                acc[a][j] = fmaf(av[a].x, bv[j].x, acc[a][j]);
                acc[a][j] = fmaf(av[a].y, bv[j].y, acc[a][j]);
                acc[a][j] = fmaf(av[a].z, bv[j].z, acc[a][j]);
                acc[a][j] = fmaf(av[a].w, bv[j].w, acc[a][j]);
            }
    }

    float* cb = covp + ((size_t)blockIdx.x << 12);   // private slice, plain stores
    #pragma unroll
    for (int a = 0; a < 4; ++a) {
        const int row = ty + 16 * a;
        #pragma unroll
        for (int j = 0; j < 4; ++j)
            cb[(row << 6) + tx + 16 * j] = acc[a][j];
    }
}

// ---------------- Kernel C: reduce partials + corr (fp64, NaN-propagating clip) ----------
// covp holds KS unscaled partial Grams per b; the 1/(T-1) scale cancels in corr.
__global__ __launch_bounds__(256) void corr_kernel(
    const float* __restrict__ covp, float* __restrict__ out)
{
    const int i = blockIdx.x * TPB + threadIdx.x;
    if (i >= Bn * Sn * Sn) return;
    const int b = i / (Sn * Sn);
    const int rem = i % (Sn * Sn);
    const int s = rem / Sn, u = rem % Sn;

    const float* pb = covp + ((size_t)b * KS << 12);
    double csu = 0.0, css = 0.0, cuu = 0.0;
    #pragma unroll
    for (int ks = 0; ks < KS; ++ks) {
        const float* p = pb + ((size_t)ks << 12);
        csu += (double)p[(s << 6) + u];
        css += (double)p[(s << 6) + s];
        cuu += (double)p[(u << 6) + u];
    }
    double r = csu / sqrt(css * cuu);
    r = (r < -1.0) ? -1.0 : ((r > 1.0) ? 1.0 : r);   // NaN-propagating clip
    out[i] = (float)(1.0 - r);
}

extern "C" void kernel_launch(void* const* d_in, const int* in_sizes, int n_in,
                              void* d_out, int out_size, void* d_ws, size_t ws_size,
                              hipStream_t stream) {
    const float* data = (const float*)d_in[0];
    const float* W1 = (const float*)d_in[1];  const float* b1 = (const float*)d_in[2];
    const float* W2 = (const float*)d_in[3];  const float* b2 = (const float*)d_in[4];
    const float* W3 = (const float*)d_in[5];  const float* b3 = (const float*)d_in[6];
    const float* W4 = (const float*)d_in[7];  const float* b4 = (const float*)d_in[8];
    const float* W5 = (const float*)d_in[9];  const float* b5 = (const float*)d_in[10];
    float* out = (float*)d_out;

    // ws layout: y fp32 (8 MB) | covp fp32 [Bn*KS][4096] (2 MB) | Rp fp64 (32 KB)
    float* y = (float*)d_ws;
    float* covp = (float*)((char*)d_ws + (size_t)Bn * Sn * Tn * sizeof(float));
    double* Rp = (double*)((char*)covp + (size_t)Bn * KS * Sn * Sn * sizeof(float));

    // no memset needed: cov partials are fully overwritten by plain stores
    mlp_kernel<<<Bn * Sn * 4, TPB, 0, stream>>>(data, W1, b1, W2, b2, W3, b3, W4, b4, W5, b5, y, Rp);
    cov_kernel<<<Bn * KS, TPB, 0, stream>>>(y, Rp, covp);
    corr_kernel<<<(Bn * Sn * Sn + TPB - 1) / TPB, TPB, 0, stream>>>(covp, out);
}

// Round 9
// 317.839 us; speedup vs baseline: 1.0757x; 1.0757x over previous
//
#include <hip/hip_runtime.h>

typedef float v2f __attribute__((ext_vector_type(2)));

#define Bn 16
#define Sn 64
#define Cn 20
#define Tn 2048
#define TPB 256
#define KS 8            // K-slices for cov partial Grams
#define Kc (Tn / KS)    // 256
#define PITCH 260       // LDS row pitch in words (cov staging), 16B-aligned

// One MLP layer, 2 time points, PACKED over output pairs (j,j+1):
// v_pk_fma_f32 does 2 MACs/instr. Weight pair {W[c][j],W[c][j+1]} is an
// 8B contiguous wave-uniform load -> SGPR PAIR operand (free broadcast).
// Activation x is splat to a VGPR pair once per (c,sample), amortized over
// NJ/2 pk_fmas. Rationale: busy-time is invariant at ~83us across 7
// structures => ~4.2 cyc/VALU-instr sustained (issue/operand-limited, not
// count-limited); halving the instruction stream attacks exactly that.
template <int NI, int NJ>
__device__ __forceinline__ void layerP(const float (&in)[2][NI], float (&out)[2][NJ],
                                       const float* __restrict__ W,
                                       const float* __restrict__ bb)
{
    static_assert(NJ % 2 == 0, "NJ must be even for j-pair packing");
    v2f a0[NJ / 2], a1[NJ / 2];
    #pragma unroll
    for (int jp = 0; jp < NJ / 2; ++jp) {
        const v2f bp = *(const v2f*)&bb[2 * jp];   // uniform -> SGPR pair
        a0[jp] = bp; a1[jp] = bp;
    }
    #pragma unroll
    for (int c = 0; c < NI; ++c) {
        const float x0 = in[0][c], x1 = in[1][c];
        v2f xs0; xs0[0] = x0; xs0[1] = x0;          // 2 v_mov, amortized /10
        v2f xs1; xs1[0] = x1; xs1[1] = x1;
        #pragma unroll
        for (int jp = 0; jp < NJ / 2; ++jp) {
            const v2f wp = *(const v2f*)&W[c * NJ + 2 * jp];  // SGPR pair
            asm("v_pk_fma_f32 %0, %1, %2, %0" : "+v"(a0[jp]) : "v"(xs0), "s"(wp));
            asm("v_pk_fma_f32 %0, %1, %2, %0" : "+v"(a1[jp]) : "v"(xs1), "s"(wp));
        }
    }
    #pragma unroll
    for (int jp = 0; jp < NJ / 2; ++jp) {
        out[0][2 * jp]     = fmaxf(a0[jp][0], 0.f);
        out[0][2 * jp + 1] = fmaxf(a0[jp][1], 0.f);
        out[1][2 * jp]     = fmaxf(a1[jp][0], 0.f);
        out[1][2 * jp + 1] = fmaxf(a1[jp][1], 0.f);
    }
}

// ---------------- Kernel A: MLP. grid = B*S*4 ----------------
__global__ __launch_bounds__(256, 4) void mlp_kernel(
    const float* __restrict__ data,
    const float* __restrict__ W1, const float* __restrict__ b1,
    const float* __restrict__ W2, const float* __restrict__ b2,
    const float* __restrict__ W3, const float* __restrict__ b3,
    const float* __restrict__ W4, const float* __restrict__ b4,
    const float* __restrict__ W5, const float* __restrict__ b5,
    float* __restrict__ y, double* __restrict__ Rp)
{
    __shared__ double rbuf[TPB / 64];

    const int tid = threadIdx.x;
    const int bs = blockIdx.x >> 2;
    const int qt = blockIdx.x & 3;
    const float* base = data + (size_t)bs * Cn * Tn;
    const int t0 = qt * (Tn / 4) + tid * 2;

    float x[2][20], h[2][20];
    #pragma unroll
    for (int c = 0; c < 20; ++c) {
        const float2 v = *(const float2*)&base[c * Tn + t0];
        x[0][c] = v.x; x[1][c] = v.y;
    }

    layerP<20, 20>(x, h, W1, b1);   // x -> h
    layerP<20, 20>(h, x, W2, b2);   // h -> x
    layerP<20, 20>(x, h, W3, b3);   // x -> h
    float g[2][10];
    layerP<20, 10>(h, g, W4, b4);   // h -> g

    // final layer 10 -> 1 (ReLU included), scalar (NJ=1)
    float s0 = b5[0], s1 = b5[0];
    #pragma unroll
    for (int c = 0; c < 10; ++c) {
        const float w = W5[c];
        s0 = fmaf(g[0][c], w, s0);
        s1 = fmaf(g[1][c], w, s1);
    }
    s0 = fmaxf(s0, 0.f);
    s1 = fmaxf(s1, 0.f);

    float2 st; st.x = s0; st.y = s1;
    *(float2*)&y[(size_t)bs * Tn + t0] = st;

    // block row-sum for the mean: wave shuffle reduce, then 4-way LDS combine
    double r = (double)s0 + (double)s1;
    #pragma unroll
    for (int off = 32; off > 0; off >>= 1) r += __shfl_down(r, off, 64);
    if ((tid & 63) == 0) rbuf[tid >> 6] = r;
    __syncthreads();
    if (tid == 0) Rp[blockIdx.x] = rbuf[0] + rbuf[1] + rbuf[2] + rbuf[3];
}

// ---------------- Kernel B: Gram partials, NO ATOMICS (R7 form, unchanged) ----------------
// grid = Bn * KS (=128). Block (b,ks) stages 64 rows x Kc=256 centered fp32
// in LDS, computes the 64x64 partial Gram for its K-slice (4x4 per thread),
// stores to a private slice covp[(b*KS+ks)*4096 + s*64 + u].
__global__ __launch_bounds__(256) void cov_kernel(
    const float* __restrict__ y, const double* __restrict__ Rp,
    float* __restrict__ covp)
{
    __shared__ __align__(16) float S[64 * PITCH];   // ~66.5 KB
    __shared__ double smean[64];

    const int tid = threadIdx.x;
    const int b  = blockIdx.x >> 3;
    const int ks = blockIdx.x & 7;

    if (tid < 64) {
        const int q = ((b << 6) + tid) * 4;
        smean[tid] = (Rp[q] + Rp[q + 1] + Rp[q + 2] + Rp[q + 3]) * (1.0 / Tn);
    }
    __syncthreads();

    // stage: 64 rows x Kc floats, centered (fp64 mean), fp32 in LDS
    const float* ybase = y + (size_t)(b << 6) * Tn + ks * Kc;
    #pragma unroll
    for (int it = 0; it < (64 * Kc / 4) / TPB; ++it) {   // 16 iters
        const int f4 = tid + it * TPB;
        const int row = f4 >> 6;                          // Kc/4 = 64 float4 per row
        const int k4 = f4 & 63;
        const float4 v = *(const float4*)&ybase[(size_t)row * Tn + k4 * 4];
        const double m = smean[row];
        float4 c;
        c.x = (float)((double)v.x - m);
        c.y = (float)((double)v.y - m);
        c.z = (float)((double)v.z - m);
        c.w = (float)((double)v.w - m);
        *(float4*)&S[row * PITCH + k4 * 4] = c;
    }
    __syncthreads();

    // compute: thread (ty,tx) -> rows {ty+16a}, cols {tx+16j}
    const int ty = tid >> 4, tx = tid & 15;
    float acc[4][4];
    #pragma unroll
    for (int a = 0; a < 4; ++a)
        #pragma unroll
        for (int j = 0; j < 4; ++j) acc[a][j] = 0.f;

    for (int kq = 0; kq < Kc / 4; ++kq) {
        float4 av[4], bv[4];
        #pragma unroll
        for (int a = 0; a < 4; ++a) av[a] = *(const float4*)&S[(ty + 16 * a) * PITCH + kq * 4];
        #pragma unroll
        for (int j = 0; j < 4; ++j) bv[j] = *(const float4*)&S[(tx + 16 * j) * PITCH + kq * 4];
        #pragma unroll
        for (int a = 0; a < 4; ++a)
            #pragma unroll
            for (int j = 0; j < 4; ++j) {
                acc[a][j] = fmaf(av[a].x, bv[j].x, acc[a][j]);
                acc[a][j] = fmaf(av[a].y, bv[j].y, acc[a][j]);
                acc[a][j] = fmaf(av[a].z, bv[j].z, acc[a][j]);
                acc[a][j] = fmaf(av[a].w, bv[j].w, acc[a][j]);
            }
    }

    float* cb = covp + ((size_t)blockIdx.x << 12);   // private slice, plain stores
    #pragma unroll
    for (int a = 0; a < 4; ++a) {
        const int row = ty + 16 * a;
        #pragma unroll
        for (int j = 0; j < 4; ++j)
            cb[(row << 6) + tx + 16 * j] = acc[a][j];
    }
}

// ---------------- Kernel C: reduce partials + corr (fp64, NaN-propagating clip) ----------
// covp holds KS unscaled partial Grams per b; the 1/(T-1) scale cancels in corr.
__global__ __launch_bounds__(256) void corr_kernel(
    const float* __restrict__ covp, float* __restrict__ out)
{
    const int i = blockIdx.x * TPB + threadIdx.x;
    if (i >= Bn * Sn * Sn) return;
    const int b = i / (Sn * Sn);
    const int rem = i % (Sn * Sn);
    const int s = rem / Sn, u = rem % Sn;

    const float* pb = covp + ((size_t)b * KS << 12);
    double csu = 0.0, css = 0.0, cuu = 0.0;
    #pragma unroll
    for (int ks = 0; ks < KS; ++ks) {
        const float* p = pb + ((size_t)ks << 12);
        csu += (double)p[(s << 6) + u];
        css += (double)p[(s << 6) + s];
        cuu += (double)p[(u << 6) + u];
    }
    double r = csu / sqrt(css * cuu);
    r = (r < -1.0) ? -1.0 : ((r > 1.0) ? 1.0 : r);   // NaN-propagating clip
    out[i] = (float)(1.0 - r);
}

extern "C" void kernel_launch(void* const* d_in, const int* in_sizes, int n_in,
                              void* d_out, int out_size, void* d_ws, size_t ws_size,
                              hipStream_t stream) {
    const float* data = (const float*)d_in[0];
    const float* W1 = (const float*)d_in[1];  const float* b1 = (const float*)d_in[2];
    const float* W2 = (const float*)d_in[3];  const float* b2 = (const float*)d_in[4];
    const float* W3 = (const float*)d_in[5];  const float* b3 = (const float*)d_in[6];
    const float* W4 = (const float*)d_in[7];  const float* b4 = (const float*)d_in[8];
    const float* W5 = (const float*)d_in[9];  const float* b5 = (const float*)d_in[10];
    float* out = (float*)d_out;

    // ws layout: y fp32 (8 MB) | covp fp32 [Bn*KS][4096] (2 MB) | Rp fp64 (32 KB)
    float* y = (float*)d_ws;
    float* covp = (float*)((char*)d_ws + (size_t)Bn * Sn * Tn * sizeof(float));
    double* Rp = (double*)((char*)covp + (size_t)Bn * KS * Sn * Sn * sizeof(float));

    // no memset needed: cov partials are fully overwritten by plain stores
    mlp_kernel<<<Bn * Sn * 4, TPB, 0, stream>>>(data, W1, b1, W2, b2, W3, b3, W4, b4, W5, b5, y, Rp);
    cov_kernel<<<Bn * KS, TPB, 0, stream>>>(y, Rp, covp);
    corr_kernel<<<(Bn * Sn * Sn + TPB - 1) / TPB, TPB, 0, stream>>>(covp, out);
}

// Round 11
// 307.163 us; speedup vs baseline: 1.1131x; 1.0348x over previous
//
#include <hip/hip_runtime.h>

typedef float v2f __attribute__((ext_vector_type(2)));

#define Bn 16
#define Sn 64
#define Cn 20
#define Tn 2048
#define TPB 256
#define KS 8            // K-slices for cov partial Grams
#define Kc (Tn / KS)    // 256
#define PITCH 260       // LDS row pitch in words (cov staging), 16B-aligned

// LDS weight layout offsets (floats)
#define OW1 0
#define OW2 400
#define OW3 800
#define OW4 1200
#define OW5 1400
#define OB1 1410
#define OB2 1430
#define OB3 1450
#define OB4 1470
#define OB5 1480
#define WTOT 1481

// One MLP layer, SAMPLE-packed: acc[j] = {sample0_j, sample1_j} (v2f).
// Weight pair {W[c][j],W[c][j+1]} is ONE uniform-address ds_read_b64
// (hardware broadcast, conflict-free); VOP3P op_sel word-select broadcasts
// the needed half to both lanes of the pk_fma — ZERO splat movs, zero
// cross-layer repacking. R9 proved pk_fma halves VALU busy (83->54us) but
// SMEM weight fetch left 69us idle; R0 proved LDS weight fetch overlaps
// (27us idle). This combines both. ReLU is scalar fmaxf per half:
// v_pk_max_f32 does NOT exist on gfx950 (R10 assembler error).
template <int NI, int NJ>
__device__ __forceinline__ void layerK(const v2f (&in)[NI], v2f (&out)[NJ],
                                       const float* lw, const float* lb)
{
    static_assert(NJ % 2 == 0, "NJ even");
    v2f acc[NJ];
    #pragma unroll
    for (int j = 0; j < NJ; ++j) {
        const float bv = lb[j];                 // uniform ds_read_b32 broadcast
        v2f a; a[0] = bv; a[1] = bv;
        acc[j] = a;
    }
    #pragma unroll
    for (int c = 0; c < NI; ++c) {
        const v2f x = in[c];                    // both samples, register
        #pragma unroll
        for (int jp = 0; jp < NJ / 2; ++jp) {
            const v2f wp = *(const v2f*)&lw[c * NJ + 2 * jp];  // ds_read_b64 bcast
            // even j: both halves use wp.lo
            asm("v_pk_fma_f32 %0, %1, %2, %0 op_sel:[0,0,0] op_sel_hi:[1,0,1]"
                : "+v"(acc[2 * jp]) : "v"(x), "v"(wp));
            // odd j: both halves use wp.hi
            asm("v_pk_fma_f32 %0, %1, %2, %0 op_sel:[0,1,0] op_sel_hi:[1,1,1]"
                : "+v"(acc[2 * jp + 1]) : "v"(x), "v"(wp));
        }
    }
    #pragma unroll
    for (int j = 0; j < NJ; ++j) {
        v2f o;
        o[0] = fmaxf(acc[j][0], 0.f);           // v_max_f32 (no pk_max on gfx950)
        o[1] = fmaxf(acc[j][1], 0.f);
        out[j] = o;
    }
}

// ---------------- Kernel A: MLP. grid = B*S*4 ----------------
__global__ __launch_bounds__(256, 4) void mlp_kernel(
    const float* __restrict__ data,
    const float* __restrict__ W1, const float* __restrict__ b1,
    const float* __restrict__ W2, const float* __restrict__ b2,
    const float* __restrict__ W3, const float* __restrict__ b3,
    const float* __restrict__ W4, const float* __restrict__ b4,
    const float* __restrict__ W5, const float* __restrict__ b5,
    float* __restrict__ y, double* __restrict__ Rp)
{
    __shared__ float lw[WTOT + 3];              // ~5.9 KB weights+biases
    __shared__ double rbuf[TPB / 64];

    const int tid = threadIdx.x;

    // stage all weights/biases to LDS once (coalesced, one-time)
    for (int i = tid; i < 400; i += TPB) { lw[OW1 + i] = W1[i]; lw[OW2 + i] = W2[i]; lw[OW3 + i] = W3[i]; }
    if (tid < 200) lw[OW4 + tid] = W4[tid];
    if (tid < 20)  { lw[OB1 + tid] = b1[tid]; lw[OB2 + tid] = b2[tid]; lw[OB3 + tid] = b3[tid]; }
    if (tid < 10)  { lw[OW5 + tid] = W5[tid]; lw[OB4 + tid] = b4[tid]; }
    if (tid == 0)  lw[OB5] = b5[0];
    __syncthreads();

    const int bs = blockIdx.x >> 2;
    const int qt = blockIdx.x & 3;
    const float* base = data + (size_t)bs * Cn * Tn;
    const int t0 = qt * (Tn / 4) + tid * 2;

    v2f x[20], h[20];
    #pragma unroll
    for (int c = 0; c < 20; ++c)
        x[c] = *(const v2f*)&base[c * Tn + t0];   // {t0, t0+1}, 8B aligned

    layerK<20, 20>(x, h, &lw[OW1], &lw[OB1]);
    layerK<20, 20>(h, x, &lw[OW2], &lw[OB2]);
    layerK<20, 20>(x, h, &lw[OW3], &lw[OB3]);
    v2f g[10];
    layerK<20, 10>(h, g, &lw[OW4], &lw[OB4]);

    // final layer 10 -> 1 (ReLU included): 5 weight pairs, op_sel alternating
    const float b5v = lw[OB5];
    v2f o; o[0] = b5v; o[1] = b5v;
    #pragma unroll
    for (int cp = 0; cp < 5; ++cp) {
        const v2f wp = *(const v2f*)&lw[OW5 + 2 * cp];
        asm("v_pk_fma_f32 %0, %1, %2, %0 op_sel:[0,0,0] op_sel_hi:[1,0,1]"
            : "+v"(o) : "v"(g[2 * cp]), "v"(wp));
        asm("v_pk_fma_f32 %0, %1, %2, %0 op_sel:[0,1,0] op_sel_hi:[1,1,1]"
            : "+v"(o) : "v"(g[2 * cp + 1]), "v"(wp));
    }
    o[0] = fmaxf(o[0], 0.f);
    o[1] = fmaxf(o[1], 0.f);

    *(v2f*)&y[(size_t)bs * Tn + t0] = o;

    // block row-sum for the mean: wave shuffle reduce, then 4-way LDS combine
    double r = (double)o[0] + (double)o[1];
    #pragma unroll
    for (int off = 32; off > 0; off >>= 1) r += __shfl_down(r, off, 64);
    if ((tid & 63) == 0) rbuf[tid >> 6] = r;
    __syncthreads();
    if (tid == 0) Rp[blockIdx.x] = rbuf[0] + rbuf[1] + rbuf[2] + rbuf[3];
}

// ---------------- Kernel B: Gram partials, NO ATOMICS (R7 form, unchanged) ----------------
__global__ __launch_bounds__(256) void cov_kernel(
    const float* __restrict__ y, const double* __restrict__ Rp,
    float* __restrict__ covp)
{
    __shared__ __align__(16) float S[64 * PITCH];   // ~66.5 KB
    __shared__ double smean[64];

    const int tid = threadIdx.x;
    const int b  = blockIdx.x >> 3;
    const int ks = blockIdx.x & 7;

    if (tid < 64) {
        const int q = ((b << 6) + tid) * 4;
        smean[tid] = (Rp[q] + Rp[q + 1] + Rp[q + 2] + Rp[q + 3]) * (1.0 / Tn);
    }
    __syncthreads();

    const float* ybase = y + (size_t)(b << 6) * Tn + ks * Kc;
    #pragma unroll
    for (int it = 0; it < (64 * Kc / 4) / TPB; ++it) {   // 16 iters
        const int f4 = tid + it * TPB;
        const int row = f4 >> 6;
        const int k4 = f4 & 63;
        const float4 v = *(const float4*)&ybase[(size_t)row * Tn + k4 * 4];
        const double m = smean[row];
        float4 c;
        c.x = (float)((double)v.x - m);
        c.y = (float)((double)v.y - m);
        c.z = (float)((double)v.z - m);
        c.w = (float)((double)v.w - m);
        *(float4*)&S[row * PITCH + k4 * 4] = c;
    }
    __syncthreads();

    const int ty = tid >> 4, tx = tid & 15;
    float acc[4][4];
    #pragma unroll
    for (int a = 0; a < 4; ++a)
        #pragma unroll
        for (int j = 0; j < 4; ++j) acc[a][j] = 0.f;

    for (int kq = 0; kq < Kc / 4; ++kq) {
        float4 av[4], bv[4];
        #pragma unroll
        for (int a = 0; a < 4; ++a) av[a] = *(const float4*)&S[(ty + 16 * a) * PITCH + kq * 4];
        #pragma unroll
        for (int j = 0; j < 4; ++j) bv[j] = *(const float4*)&S[(tx + 16 * j) * PITCH + kq * 4];
        #pragma unroll
        for (int a = 0; a < 4; ++a)
            #pragma unroll
            for (int j = 0; j < 4; ++j) {
                acc[a][j] = fmaf(av[a].x, bv[j].x, acc[a][j]);
                acc[a][j] = fmaf(av[a].y, bv[j].y, acc[a][j]);
                acc[a][j] = fmaf(av[a].z, bv[j].z, acc[a][j]);
                acc[a][j] = fmaf(av[a].w, bv[j].w, acc[a][j]);
            }
    }

    float* cb = covp + ((size_t)blockIdx.x << 12);
    #pragma unroll
    for (int a = 0; a < 4; ++a) {
        const int row = ty + 16 * a;
        #pragma unroll
        for (int j = 0; j < 4; ++j)
            cb[(row << 6) + tx + 16 * j] = acc[a][j];
    }
}

// ---------------- Kernel C: reduce partials + corr (fp64, NaN-propagating clip) ----------
__global__ __launch_bounds__(256) void corr_kernel(
    const float* __restrict__ covp, float* __restrict__ out)
{
    const int i = blockIdx.x * TPB + threadIdx.x;
    if (i >= Bn * Sn * Sn) return;
    const int b = i / (Sn * Sn);
    const int rem = i % (Sn * Sn);
    const int s = rem / Sn, u = rem % Sn;

    const float* pb = covp + ((size_t)b * KS << 12);
    double csu = 0.0, css = 0.0, cuu = 0.0;
    #pragma unroll
    for (int ks = 0; ks < KS; ++ks) {
        const float* p = pb + ((size_t)ks << 12);
        csu += (double)p[(s << 6) + u];
        css += (double)p[(s << 6) + s];
        cuu += (double)p[(u << 6) + u];
    }
    double r = csu / sqrt(css * cuu);
    r = (r < -1.0) ? -1.0 : ((r > 1.0) ? 1.0 : r);   // NaN-propagating clip
    out[i] = (float)(1.0 - r);
}

extern "C" void kernel_launch(void* const* d_in, const int* in_sizes, int n_in,
                              void* d_out, int out_size, void* d_ws, size_t ws_size,
                              hipStream_t stream) {
    const float* data = (const float*)d_in[0];
    const float* W1 = (const float*)d_in[1];  const float* b1 = (const float*)d_in[2];
    const float* W2 = (const float*)d_in[3];  const float* b2 = (const float*)d_in[4];
    const float* W3 = (const float*)d_in[5];  const float* b3 = (const float*)d_in[6];
    const float* W4 = (const float*)d_in[7];  const float* b4 = (const float*)d_in[8];
    const float* W5 = (const float*)d_in[9];  const float* b5 = (const float*)d_in[10];
    float* out = (float*)d_out;

    // ws layout: y fp32 (8 MB) | covp fp32 [Bn*KS][4096] (2 MB) | Rp fp64 (32 KB)
    float* y = (float*)d_ws;
    float* covp = (float*)((char*)d_ws + (size_t)Bn * Sn * Tn * sizeof(float));
    double* Rp = (double*)((char*)covp + (size_t)Bn * KS * Sn * Sn * sizeof(float));

    mlp_kernel<<<Bn * Sn * 4, TPB, 0, stream>>>(data, W1, b1, W2, b2, W3, b3, W4, b4, W5, b5, y, Rp);
    cov_kernel<<<Bn * KS, TPB, 0, stream>>>(y, Rp, covp);
    corr_kernel<<<(Bn * Sn * Sn + TPB - 1) / TPB, TPB, 0, stream>>>(covp, out);
}